// Round 4
// baseline (348.705 us; speedup 1.0000x reference)
//
#include <hip/hip_runtime.h>
#include <stdint.h>

// RelationalMSG decomposed (R4):
//   msg  = relu(x_s@W1a + x_d@W1b + b1)  ->  Ys = x@W1a, Yd = x@W1b + b1  (dense GEMM, fused fp32->bf16)
//   agg  = segment_sum(msg, dst)         ->  counting-sort by dst (hist/scan/scatter), CSR gather-sum, NO atomics
//   out  = x + relu([x;agg]@W2 + b2)     ->  dense GEMM (A converted inline from fp32 x / bf16 aggb)
// Ys/Yd/aggb live in a column-PERMUTED layout pos = c16*8 + ct  (c = ct*16 + c16);
// the inverse permutation is baked into w2f's fragment conversion. 7 dispatches total.
// N=50000, E=600000, D=128.

typedef __attribute__((ext_vector_type(8))) short short8;   // 8 bf16 (MFMA A/B frag)
typedef __attribute__((ext_vector_type(4))) float floatx4;  // MFMA C/D frag

#define D 128

static __device__ __forceinline__ unsigned short f2bf(float f) {
    union { float f; unsigned int u; } v; v.f = f;
    unsigned int r = (v.u + 0x7fffu + ((v.u >> 16) & 1u)) >> 16; // RNE
    return (unsigned short)r;
}
static __device__ __forceinline__ float bflo(unsigned int u) {
    union { unsigned int u; float f; } v; v.u = u << 16; return v.f;
}
static __device__ __forceinline__ float bfhi(unsigned int u) {
    union { unsigned int u; float f; } v; v.u = u & 0xffff0000u; return v.f;
}
static __device__ __forceinline__ short8 cvt8(const float* p) {
    float4 f0 = *(const float4*)p;
    float4 f1 = *(const float4*)(p + 4);
    short8 t;
    t[0] = (short)f2bf(f0.x); t[1] = (short)f2bf(f0.y);
    t[2] = (short)f2bf(f0.z); t[3] = (short)f2bf(f0.w);
    t[4] = (short)f2bf(f1.x); t[5] = (short)f2bf(f1.y);
    t[6] = (short)f2bf(f1.z); t[7] = (short)f2bf(f1.w);
    return t;
}

// B-fragment conversion for both weights + zero the histogram buffer.
// w1f (gemm1, K=128, 256 cols): frag[(kk*16+ct)*64+lane][j] = B1[kk*32+(lane>>4)*8+j][ct*16+(lane&15)]
//   B1[k][c] = c<128 ? W1[k][c] : W1[128+k][c-128]
// w2f (gemm2, K=256, 128 cols): k<128 -> W2 row k; k>=128 -> W2 row 128 + invperm(k-128),
//   invperm(p) = (p&7)*16 + (p>>3)   (undoes the Ys/Yd/aggb storage permutation)
__global__ void k_convert_w(const float* __restrict__ W1, const float* __restrict__ W2,
                            unsigned short* __restrict__ w1f, unsigned short* __restrict__ w2f,
                            int* __restrict__ cnt, int N) {
    int gid = blockIdx.x * blockDim.x + threadIdx.x; // 65536 threads
    if (gid < N) cnt[gid] = 0;
    if (gid < 32768) {
        int tid = gid;
        int j = tid & 7, lane = (tid >> 3) & 63, ct = (tid >> 9) & 15, kk = tid >> 13;
        int k = kk * 32 + (lane >> 4) * 8 + j;
        int c = ct * 16 + (lane & 15);
        float v = (c < 128) ? W1[k * 128 + c] : W1[(128 + k) * 128 + (c - 128)];
        w1f[tid] = f2bf(v);
    } else {
        int tid = gid - 32768;
        int j = tid & 7, lane = (tid >> 3) & 63, ct = (tid >> 9) & 7, kk = tid >> 12;
        int k = kk * 32 + (lane >> 4) * 8 + j;
        int c = ct * 16 + (lane & 15);
        int row = (k < 128) ? k : (128 + ((k - 128) & 7) * 16 + ((k - 128) >> 3));
        w2f[tid] = f2bf(W2[row * 128 + c]);
    }
}

// [Ys | Yd] = x @ [W1a | W1b] (+b1 on Yd), output bf16 in permuted layout.
// Block = 4 waves; waves 0,1 -> Ys cols, waves 2,3 -> Yd cols. Barrier-free.
__global__ __launch_bounds__(256) void k_gemm1(
    const float* __restrict__ x,
    const unsigned short* __restrict__ w1f,
    const float* __restrict__ b1,
    unsigned short* __restrict__ Ys,
    unsigned short* __restrict__ Yd,
    int N, int nTiles)
{
    const int tid = threadIdx.x, w = tid >> 6, lane = tid & 63;
    const int quad = lane >> 4, col = lane & 15;

    short8 wf[4][4];
#pragma unroll
    for (int kk = 0; kk < 4; kk++)
#pragma unroll
        for (int j = 0; j < 4; j++)
            wf[kk][j] = ((const short8*)w1f)[(kk * 16 + w * 4 + j) * 64 + lane];
    float bias[4];
#pragma unroll
    for (int j = 0; j < 4; j++)
        bias[j] = (w >= 2) ? b1[(((w & 1) * 4 + j)) * 16 + col] : 0.f;
    unsigned short* Yhalf = (w < 2) ? Ys : Yd;
    const int ctb = (w & 1) * 4;   // permuted store base: pos = col16*8 + ct

    for (int t = blockIdx.x; t < nTiles; t += gridDim.x) {
        const int n0 = t * 16;
        int nr = n0 + col; if (nr >= N) nr = N - 1;
        floatx4 acc[4];
#pragma unroll
        for (int j = 0; j < 4; j++)
#pragma unroll
            for (int q = 0; q < 4; q++) acc[j][q] = 0.f;
#pragma unroll
        for (int kk = 0; kk < 4; kk++) {
            short8 a = cvt8(x + (long)nr * D + kk * 32 + quad * 8);
#pragma unroll
            for (int j = 0; j < 4; j++)
                acc[j] = __builtin_amdgcn_mfma_f32_16x16x32_bf16(a, wf[kk][j], acc[j], 0, 0, 0);
        }
#pragma unroll
        for (int r = 0; r < 4; r++) {
            int n = n0 + quad * 4 + r;
            if (n < N) {
                ushort4 o;
                o.x = f2bf(acc[0][r] + bias[0]);
                o.y = f2bf(acc[1][r] + bias[1]);
                o.z = f2bf(acc[2][r] + bias[2]);
                o.w = f2bf(acc[3][r] + bias[3]);
                *(ushort4*)(Yhalf + (long)n * D + col * 8 + ctb) = o;
            }
        }
    }
}

__global__ void k_hist(const int* __restrict__ dst, int* __restrict__ cnt, int E) {
    int i = blockIdx.x * blockDim.x + threadIdx.x;
    if (i < E) atomicAdd(&cnt[dst[i]], 1);
}

// Single-block scan: per-thread serial sum of `per` elements -> block scan -> rewrite.
__global__ __launch_bounds__(1024) void k_scan(const int* __restrict__ cnt,
                                               int* __restrict__ rowptr,
                                               int* __restrict__ cursor, int N, int E) {
    __shared__ int s[1024];
    const int tid = threadIdx.x;
    const int per = (N + 1023) / 1024;
    const int base = tid * per;
    int sum = 0;
    for (int i = 0; i < per; i++) {
        int idx = base + i;
        if (idx < N) sum += cnt[idx];
    }
    s[tid] = sum; __syncthreads();
    for (int off = 1; off < 1024; off <<= 1) {
        int t = (tid >= off) ? s[tid - off] : 0;
        __syncthreads();
        s[tid] += t;
        __syncthreads();
    }
    int run = s[tid] - sum;   // exclusive prefix of this thread's chunk
    for (int i = 0; i < per; i++) {
        int idx = base + i;
        if (idx < N) {
            rowptr[idx] = run;
            cursor[idx] = run;
            run += cnt[idx];
        }
    }
    if (tid == 0) rowptr[N] = E;
}

__global__ void k_scatter(const int* __restrict__ src, const int* __restrict__ dst,
                          int* __restrict__ cursor, int* __restrict__ ssrc, int E) {
    int i = blockIdx.x * blockDim.x + threadIdx.x;
    if (i < E) {
        int p = atomicAdd(&cursor[dst[i]], 1);
        ssrc[p] = src[i];
    }
}

// CSR aggregation: one wave per dst node; lane owns 2 permuted cols (4B).
// aggb[n] = sum_e relu(Ys[src_e] + Yd[n])  (all in permuted col space). No atomics.
__global__ __launch_bounds__(256) void k_agg(
    const unsigned short* __restrict__ Ys,
    const unsigned short* __restrict__ Yd,
    const int* __restrict__ rowptr,
    const int* __restrict__ ssrc,
    unsigned short* __restrict__ aggb, int N)
{
    int wv = blockIdx.x * 4 + (threadIdx.x >> 6);
    if (wv >= N) return;
    int lane = threadIdx.x & 63;
    int rp0 = rowptr[wv], rp1 = rowptr[wv + 1];
    unsigned int ydu = *(const unsigned int*)(Yd + (long)wv * D + lane * 2);
    float yd0 = bflo(ydu), yd1 = bfhi(ydu);
    float a0 = 0.f, a1 = 0.f;
    int e = rp0;
    for (; e + 4 <= rp1; e += 4) {
        int s0 = ssrc[e], s1 = ssrc[e + 1], s2 = ssrc[e + 2], s3 = ssrc[e + 3];
        unsigned int u0 = *(const unsigned int*)(Ys + (long)s0 * D + lane * 2);
        unsigned int u1 = *(const unsigned int*)(Ys + (long)s1 * D + lane * 2);
        unsigned int u2 = *(const unsigned int*)(Ys + (long)s2 * D + lane * 2);
        unsigned int u3 = *(const unsigned int*)(Ys + (long)s3 * D + lane * 2);
        a0 += fmaxf(bflo(u0) + yd0, 0.f); a1 += fmaxf(bfhi(u0) + yd1, 0.f);
        a0 += fmaxf(bflo(u1) + yd0, 0.f); a1 += fmaxf(bfhi(u1) + yd1, 0.f);
        a0 += fmaxf(bflo(u2) + yd0, 0.f); a1 += fmaxf(bfhi(u2) + yd1, 0.f);
        a0 += fmaxf(bflo(u3) + yd0, 0.f); a1 += fmaxf(bfhi(u3) + yd1, 0.f);
    }
    for (; e < rp1; e++) {
        int s0 = ssrc[e];
        unsigned int u0 = *(const unsigned int*)(Ys + (long)s0 * D + lane * 2);
        a0 += fmaxf(bflo(u0) + yd0, 0.f); a1 += fmaxf(bfhi(u0) + yd1, 0.f);
    }
    unsigned int o = (unsigned int)f2bf(a0) | ((unsigned int)f2bf(a1) << 16);
    *(unsigned int*)(aggb + (long)wv * D + lane * 2) = o;
}

// out = x + relu([x ; agg] @ W2 + b2). A first half converted inline from fp32 x,
// second half from permuted aggb (w2f already un-permutes). Barrier-free.
__global__ __launch_bounds__(256) void k_gemm2(
    const float* __restrict__ x,
    const unsigned short* __restrict__ aggb,
    const unsigned short* __restrict__ w2f,
    const float* __restrict__ b2,
    float* __restrict__ out,
    int N, int nTiles)
{
    const int tid = threadIdx.x, w = tid >> 6, lane = tid & 63;
    const int quad = lane >> 4, col = lane & 15;

    short8 wf[8][2];
#pragma unroll
    for (int kk = 0; kk < 8; kk++)
#pragma unroll
        for (int c = 0; c < 2; c++)
            wf[kk][c] = ((const short8*)w2f)[(kk * 8 + w * 2 + c) * 64 + lane];
    float bias[2];
    bias[0] = b2[(w * 2) * 16 + col];
    bias[1] = b2[(w * 2 + 1) * 16 + col];

    for (int t = blockIdx.x; t < nTiles; t += gridDim.x) {
        const int n0 = t * 16;
        int nr = n0 + col; if (nr >= N) nr = N - 1;
        floatx4 acc[2];
#pragma unroll
        for (int c = 0; c < 2; c++)
#pragma unroll
            for (int q = 0; q < 4; q++) acc[c][q] = 0.f;
#pragma unroll
        for (int kk = 0; kk < 8; kk++) {
            short8 a;
            if (kk < 4)
                a = cvt8(x + (long)nr * D + kk * 32 + quad * 8);
            else
                a = *(const short8*)(aggb + (long)nr * D + (kk - 4) * 32 + quad * 8);
            acc[0] = __builtin_amdgcn_mfma_f32_16x16x32_bf16(a, wf[kk][0], acc[0], 0, 0, 0);
            acc[1] = __builtin_amdgcn_mfma_f32_16x16x32_bf16(a, wf[kk][1], acc[1], 0, 0, 0);
        }
#pragma unroll
        for (int c = 0; c < 2; c++)
#pragma unroll
            for (int r = 0; r < 4; r++) {
                int n = n0 + quad * 4 + r;
                if (n < N) {
                    long idx = (long)n * D + (w * 2 + c) * 16 + col;
                    float v = acc[c][r] + bias[c];
                    v = v > 0.f ? v : 0.f;
                    out[idx] = x[idx] + v;
                }
            }
    }
}

extern "C" void kernel_launch(void* const* d_in, const int* in_sizes, int n_in,
                              void* d_out, int out_size, void* d_ws, size_t ws_size,
                              hipStream_t stream)
{
    const float* x   = (const float*)d_in[0];
    const int* esrc  = (const int*)d_in[1];
    const int* edst  = (const int*)d_in[2];
    const float* W1  = (const float*)d_in[3];
    const float* b1  = (const float*)d_in[4];
    const float* W2  = (const float*)d_in[5];
    const float* b2  = (const float*)d_in[6];
    float* out = (float*)d_out;

    const int ND = in_sizes[0];     // N*D
    const int N  = ND / D;          // 50000
    const int E  = in_sizes[1];     // 600000

    // workspace carve-out (256B-aligned), total ~42 MB
    char* p = (char*)d_ws;
    auto alloc = [&](size_t bytes) { char* r = p; p += (bytes + 255) & ~(size_t)255; return r; };
    unsigned short* Ys   = (unsigned short*)alloc((size_t)ND * 2);
    unsigned short* Yd   = (unsigned short*)alloc((size_t)ND * 2);
    unsigned short* aggb = (unsigned short*)alloc((size_t)ND * 2);
    unsigned short* w1f  = (unsigned short*)alloc(32768 * 2);
    unsigned short* w2f  = (unsigned short*)alloc(32768 * 2);
    int* rowptr = (int*)alloc((size_t)(N + 1) * 4);
    int* cursor = (int*)alloc((size_t)N * 4);
    int* cnt    = (int*)alloc((size_t)N * 4);
    int* ssrc   = (int*)alloc((size_t)E * 4);

    k_convert_w<<<256, 256, 0, stream>>>(W1, W2, w1f, w2f, cnt, N);

    const int nTiles = (N + 15) / 16;   // 3125
    k_gemm1<<<640, 256, 0, stream>>>(x, w1f, b1, Ys, Yd, N, nTiles);

    k_hist<<<(E + 255) / 256, 256, 0, stream>>>(edst, cnt, E);
    k_scan<<<1, 1024, 0, stream>>>(cnt, rowptr, cursor, N, E);
    k_scatter<<<(E + 255) / 256, 256, 0, stream>>>(esrc, edst, cursor, ssrc, E);

    k_agg<<<(N + 3) / 4, 256, 0, stream>>>(Ys, Yd, rowptr, ssrc, aggb, N);

    k_gemm2<<<640, 256, 0, stream>>>(x, aggb, w2f, b2, out, N, nTiles);
}

// Round 5
// 229.404 us; speedup vs baseline: 1.5200x; 1.5200x over previous
//
#include <hip/hip_runtime.h>
#include <stdint.h>

// RelationalMSG decomposed (R5 = R4 with the parallel 3-stage scan restored):
//   msg  = relu(x_s@W1a + x_d@W1b + b1)  ->  Ys = x@W1a, Yd = x@W1b + b1  (dense GEMM, fused fp32->bf16)
//   agg  = segment_sum(msg, dst)         ->  counting-sort by dst (hist/scanA/B/C/scatter), CSR gather-sum
//   out  = x + relu([x;agg]@W2 + b2)     ->  dense GEMM (A converted inline)
// Ys/Yd/aggb in column-permuted layout pos = c16*8 + ct; inverse baked into w2f frags.
// N=50000, E=600000, D=128. 9 dispatches, no fp32 atomics anywhere.

typedef __attribute__((ext_vector_type(8))) short short8;   // 8 bf16 (MFMA A/B frag)
typedef __attribute__((ext_vector_type(4))) float floatx4;  // MFMA C/D frag

#define D 128

static __device__ __forceinline__ unsigned short f2bf(float f) {
    union { float f; unsigned int u; } v; v.f = f;
    unsigned int r = (v.u + 0x7fffu + ((v.u >> 16) & 1u)) >> 16; // RNE
    return (unsigned short)r;
}
static __device__ __forceinline__ float bflo(unsigned int u) {
    union { unsigned int u; float f; } v; v.u = u << 16; return v.f;
}
static __device__ __forceinline__ float bfhi(unsigned int u) {
    union { unsigned int u; float f; } v; v.u = u & 0xffff0000u; return v.f;
}
static __device__ __forceinline__ short8 cvt8(const float* p) {
    float4 f0 = *(const float4*)p;
    float4 f1 = *(const float4*)(p + 4);
    short8 t;
    t[0] = (short)f2bf(f0.x); t[1] = (short)f2bf(f0.y);
    t[2] = (short)f2bf(f0.z); t[3] = (short)f2bf(f0.w);
    t[4] = (short)f2bf(f1.x); t[5] = (short)f2bf(f1.y);
    t[6] = (short)f2bf(f1.z); t[7] = (short)f2bf(f1.w);
    return t;
}

// B-fragment conversion for both weights + zero the histogram buffer.
// w1f (gemm1, K=128, 256 cols): frag[(kk*16+ct)*64+lane][j] = B1[kk*32+(lane>>4)*8+j][ct*16+(lane&15)]
//   B1[k][c] = c<128 ? W1[k][c] : W1[128+k][c-128]
// w2f (gemm2, K=256, 128 cols): k<128 -> W2 row k; k>=128 -> W2 row 128+invperm(k-128),
//   invperm(p) = (p&7)*16 + (p>>3)
__global__ void k_convert_w(const float* __restrict__ W1, const float* __restrict__ W2,
                            unsigned short* __restrict__ w1f, unsigned short* __restrict__ w2f,
                            int* __restrict__ cnt, int N) {
    int gid = blockIdx.x * blockDim.x + threadIdx.x; // 65536 threads
    if (gid < N) cnt[gid] = 0;
    if (gid < 32768) {
        int tid = gid;
        int j = tid & 7, lane = (tid >> 3) & 63, ct = (tid >> 9) & 15, kk = tid >> 13;
        int k = kk * 32 + (lane >> 4) * 8 + j;
        int c = ct * 16 + (lane & 15);
        float v = (c < 128) ? W1[k * 128 + c] : W1[(128 + k) * 128 + (c - 128)];
        w1f[tid] = f2bf(v);
    } else {
        int tid = gid - 32768;
        int j = tid & 7, lane = (tid >> 3) & 63, ct = (tid >> 9) & 7, kk = tid >> 12;
        int k = kk * 32 + (lane >> 4) * 8 + j;
        int c = ct * 16 + (lane & 15);
        int row = (k < 128) ? k : (128 + ((k - 128) & 7) * 16 + ((k - 128) >> 3));
        w2f[tid] = f2bf(W2[row * 128 + c]);
    }
}

// [Ys | Yd] = x @ [W1a | W1b] (+b1 on Yd), bf16 out in permuted layout. Barrier-free.
__global__ __launch_bounds__(256) void k_gemm1(
    const float* __restrict__ x,
    const unsigned short* __restrict__ w1f,
    const float* __restrict__ b1,
    unsigned short* __restrict__ Ys,
    unsigned short* __restrict__ Yd,
    int N, int nTiles)
{
    const int tid = threadIdx.x, w = tid >> 6, lane = tid & 63;
    const int quad = lane >> 4, col = lane & 15;

    short8 wf[4][4];
#pragma unroll
    for (int kk = 0; kk < 4; kk++)
#pragma unroll
        for (int j = 0; j < 4; j++)
            wf[kk][j] = ((const short8*)w1f)[(kk * 16 + w * 4 + j) * 64 + lane];
    float bias[4];
#pragma unroll
    for (int j = 0; j < 4; j++)
        bias[j] = (w >= 2) ? b1[(((w & 1) * 4 + j)) * 16 + col] : 0.f;
    unsigned short* Yhalf = (w < 2) ? Ys : Yd;
    const int ctb = (w & 1) * 4;   // permuted store base: pos = col16*8 + ct

    for (int t = blockIdx.x; t < nTiles; t += gridDim.x) {
        const int n0 = t * 16;
        int nr = n0 + col; if (nr >= N) nr = N - 1;
        floatx4 acc[4];
#pragma unroll
        for (int j = 0; j < 4; j++)
#pragma unroll
            for (int q = 0; q < 4; q++) acc[j][q] = 0.f;
#pragma unroll
        for (int kk = 0; kk < 4; kk++) {
            short8 a = cvt8(x + (long)nr * D + kk * 32 + quad * 8);
#pragma unroll
            for (int j = 0; j < 4; j++)
                acc[j] = __builtin_amdgcn_mfma_f32_16x16x32_bf16(a, wf[kk][j], acc[j], 0, 0, 0);
        }
#pragma unroll
        for (int r = 0; r < 4; r++) {
            int n = n0 + quad * 4 + r;
            if (n < N) {
                ushort4 o;
                o.x = f2bf(acc[0][r] + bias[0]);
                o.y = f2bf(acc[1][r] + bias[1]);
                o.z = f2bf(acc[2][r] + bias[2]);
                o.w = f2bf(acc[3][r] + bias[3]);
                *(ushort4*)(Yhalf + (long)n * D + col * 8 + ctb) = o;
            }
        }
    }
}

__global__ void k_hist(const int* __restrict__ dst, int* __restrict__ cnt, int E) {
    int i = blockIdx.x * blockDim.x + threadIdx.x;
    if (i < E) atomicAdd(&cnt[dst[i]], 1);
}

// Parallel scan, 3 stages (proven in R3; one-block version was 128us -> reverted).
__global__ __launch_bounds__(1024) void k_scanA(const int* __restrict__ cnt,
                                                int* __restrict__ rowptr,
                                                int* __restrict__ bsum, int N) {
    __shared__ int s[1024];
    int tid = threadIdx.x, i = blockIdx.x * 1024 + tid;
    int c = (i < N) ? cnt[i] : 0;
    s[tid] = c; __syncthreads();
    for (int off = 1; off < 1024; off <<= 1) {
        int t = (tid >= off) ? s[tid - off] : 0;
        __syncthreads();
        s[tid] += t;
        __syncthreads();
    }
    if (i < N) rowptr[i] = s[tid] - c;           // exclusive within block
    if (tid == 1023) bsum[blockIdx.x] = s[1023]; // block total
}

__global__ void k_scanB(int* __restrict__ bsum, int nb) {
    int lane = threadIdx.x; // single wave; nb <= 64
    int v = (lane < nb) ? bsum[lane] : 0;
    int incl = v;
    for (int off = 1; off < 64; off <<= 1) {
        int t = __shfl_up(incl, off, 64);
        if (lane >= off) incl += t;
    }
    if (lane < nb) bsum[lane] = incl - v;        // exclusive block offsets
}

__global__ void k_scanC(int* __restrict__ rowptr, int* __restrict__ cursor,
                        const int* __restrict__ bsum, int N, int E) {
    int i = blockIdx.x * blockDim.x + threadIdx.x;
    if (i < N) {
        int r = rowptr[i] + bsum[i >> 10];
        rowptr[i] = r;
        cursor[i] = r;
    }
    if (i == 0) rowptr[N] = E;
}

__global__ void k_scatter(const int* __restrict__ src, const int* __restrict__ dst,
                          int* __restrict__ cursor, int* __restrict__ ssrc, int E) {
    int i = blockIdx.x * blockDim.x + threadIdx.x;
    if (i < E) {
        int p = atomicAdd(&cursor[dst[i]], 1);
        ssrc[p] = src[i];
    }
}

// CSR aggregation: one wave per dst node; lane owns 2 permuted cols (4B). No atomics.
__global__ __launch_bounds__(256) void k_agg(
    const unsigned short* __restrict__ Ys,
    const unsigned short* __restrict__ Yd,
    const int* __restrict__ rowptr,
    const int* __restrict__ ssrc,
    unsigned short* __restrict__ aggb, int N)
{
    int wv = blockIdx.x * 4 + (threadIdx.x >> 6);
    if (wv >= N) return;
    int lane = threadIdx.x & 63;
    int rp0 = rowptr[wv], rp1 = rowptr[wv + 1];
    unsigned int ydu = *(const unsigned int*)(Yd + (long)wv * D + lane * 2);
    float yd0 = bflo(ydu), yd1 = bfhi(ydu);
    float a0 = 0.f, a1 = 0.f;
    int e = rp0;
    for (; e + 4 <= rp1; e += 4) {
        int s0 = ssrc[e], s1 = ssrc[e + 1], s2 = ssrc[e + 2], s3 = ssrc[e + 3];
        unsigned int u0 = *(const unsigned int*)(Ys + (long)s0 * D + lane * 2);
        unsigned int u1 = *(const unsigned int*)(Ys + (long)s1 * D + lane * 2);
        unsigned int u2 = *(const unsigned int*)(Ys + (long)s2 * D + lane * 2);
        unsigned int u3 = *(const unsigned int*)(Ys + (long)s3 * D + lane * 2);
        a0 += fmaxf(bflo(u0) + yd0, 0.f); a1 += fmaxf(bfhi(u0) + yd1, 0.f);
        a0 += fmaxf(bflo(u1) + yd0, 0.f); a1 += fmaxf(bfhi(u1) + yd1, 0.f);
        a0 += fmaxf(bflo(u2) + yd0, 0.f); a1 += fmaxf(bfhi(u2) + yd1, 0.f);
        a0 += fmaxf(bflo(u3) + yd0, 0.f); a1 += fmaxf(bfhi(u3) + yd1, 0.f);
    }
    for (; e < rp1; e++) {
        int s0 = ssrc[e];
        unsigned int u0 = *(const unsigned int*)(Ys + (long)s0 * D + lane * 2);
        a0 += fmaxf(bflo(u0) + yd0, 0.f); a1 += fmaxf(bfhi(u0) + yd1, 0.f);
    }
    unsigned int o = (unsigned int)f2bf(a0) | ((unsigned int)f2bf(a1) << 16);
    *(unsigned int*)(aggb + (long)wv * D + lane * 2) = o;
}

// out = x + relu([x ; agg] @ W2 + b2). A converted inline; w2f un-permutes agg cols.
__global__ __launch_bounds__(256) void k_gemm2(
    const float* __restrict__ x,
    const unsigned short* __restrict__ aggb,
    const unsigned short* __restrict__ w2f,
    const float* __restrict__ b2,
    float* __restrict__ out,
    int N, int nTiles)
{
    const int tid = threadIdx.x, w = tid >> 6, lane = tid & 63;
    const int quad = lane >> 4, col = lane & 15;

    short8 wf[8][2];
#pragma unroll
    for (int kk = 0; kk < 8; kk++)
#pragma unroll
        for (int c = 0; c < 2; c++)
            wf[kk][c] = ((const short8*)w2f)[(kk * 8 + w * 2 + c) * 64 + lane];
    float bias[2];
    bias[0] = b2[(w * 2) * 16 + col];
    bias[1] = b2[(w * 2 + 1) * 16 + col];

    for (int t = blockIdx.x; t < nTiles; t += gridDim.x) {
        const int n0 = t * 16;
        int nr = n0 + col; if (nr >= N) nr = N - 1;
        floatx4 acc[2];
#pragma unroll
        for (int c = 0; c < 2; c++)
#pragma unroll
            for (int q = 0; q < 4; q++) acc[c][q] = 0.f;
#pragma unroll
        for (int kk = 0; kk < 8; kk++) {
            short8 a;
            if (kk < 4)
                a = cvt8(x + (long)nr * D + kk * 32 + quad * 8);
            else
                a = *(const short8*)(aggb + (long)nr * D + (kk - 4) * 32 + quad * 8);
            acc[0] = __builtin_amdgcn_mfma_f32_16x16x32_bf16(a, wf[kk][0], acc[0], 0, 0, 0);
            acc[1] = __builtin_amdgcn_mfma_f32_16x16x32_bf16(a, wf[kk][1], acc[1], 0, 0, 0);
        }
#pragma unroll
        for (int c = 0; c < 2; c++)
#pragma unroll
            for (int r = 0; r < 4; r++) {
                int n = n0 + quad * 4 + r;
                if (n < N) {
                    long idx = (long)n * D + (w * 2 + c) * 16 + col;
                    float v = acc[c][r] + bias[c];
                    v = v > 0.f ? v : 0.f;
                    out[idx] = x[idx] + v;
                }
            }
    }
}

extern "C" void kernel_launch(void* const* d_in, const int* in_sizes, int n_in,
                              void* d_out, int out_size, void* d_ws, size_t ws_size,
                              hipStream_t stream)
{
    const float* x   = (const float*)d_in[0];
    const int* esrc  = (const int*)d_in[1];
    const int* edst  = (const int*)d_in[2];
    const float* W1  = (const float*)d_in[3];
    const float* b1  = (const float*)d_in[4];
    const float* W2  = (const float*)d_in[5];
    const float* b2  = (const float*)d_in[6];
    float* out = (float*)d_out;

    const int ND = in_sizes[0];     // N*D
    const int N  = ND / D;          // 50000
    const int E  = in_sizes[1];     // 600000

    // workspace carve-out (256B-aligned), total ~42 MB
    char* p = (char*)d_ws;
    auto alloc = [&](size_t bytes) { char* r = p; p += (bytes + 255) & ~(size_t)255; return r; };
    unsigned short* Ys   = (unsigned short*)alloc((size_t)ND * 2);
    unsigned short* Yd   = (unsigned short*)alloc((size_t)ND * 2);
    unsigned short* aggb = (unsigned short*)alloc((size_t)ND * 2);
    unsigned short* w1f  = (unsigned short*)alloc(32768 * 2);
    unsigned short* w2f  = (unsigned short*)alloc(32768 * 2);
    int* rowptr = (int*)alloc((size_t)(N + 1) * 4);
    int* cursor = (int*)alloc((size_t)N * 4);
    int* cnt    = (int*)alloc((size_t)N * 4);
    int* bsum   = (int*)alloc(64 * 4);
    int* ssrc   = (int*)alloc((size_t)E * 4);

    k_convert_w<<<256, 256, 0, stream>>>(W1, W2, w1f, w2f, cnt, N);

    const int nTiles = (N + 15) / 16;   // 3125
    k_gemm1<<<640, 256, 0, stream>>>(x, w1f, b1, Ys, Yd, N, nTiles);

    k_hist<<<(E + 255) / 256, 256, 0, stream>>>(edst, cnt, E);
    const int nb = (N + 1023) / 1024;   // 49 (<=64)
    k_scanA<<<nb, 1024, 0, stream>>>(cnt, rowptr, bsum, N);
    k_scanB<<<1, 64, 0, stream>>>(bsum, nb);
    k_scanC<<<(N + 255) / 256, 256, 0, stream>>>(rowptr, cursor, bsum, N, E);
    k_scatter<<<(E + 255) / 256, 256, 0, stream>>>(esrc, edst, cursor, ssrc, E);

    k_agg<<<(N + 3) / 4, 256, 0, stream>>>(Ys, Yd, rowptr, ssrc, aggb, N);

    k_gemm2<<<640, 256, 0, stream>>>(x, aggb, w2f, b2, out, N, nTiles);
}